// Round 3
// baseline (4481.948 us; speedup 1.0000x reference)
//
#include <hip/hip_runtime.h>
#include <math.h>

// Problem dims
#define NB   16
#define NC   1024
#define ND   256
#define NT_  9
#define TDIM 32

// MFMA GEMM tile config: 128x64 tile, BK=32, 256 threads (4 waves, 2x2),
// wave tile 64x32 = 4x2 fragments of 16x16. Double-buffered LDS (48KB).
#define BM 128
#define BN 64
#define BK 32
#define NTHR 256

typedef _Float16 half8 __attribute__((ext_vector_type(8)));
typedef _Float16 half4v __attribute__((ext_vector_type(4)));
typedef float f32x4 __attribute__((ext_vector_type(4)));

#define GLL(gp, lp)                                                            \
  __builtin_amdgcn_global_load_lds(                                            \
      (const __attribute__((address_space(1))) void*)(gp),                     \
      (__attribute__((address_space(3))) void*)(lp), 16, 0, 0)

// ---------------------------------------------------------------------------
// copy h0 -> traj[:,0]
__global__ __launch_bounds__(256) void k_copy_h0(const float* __restrict__ h0,
                                                 float* __restrict__ out) {
  size_t idx = (size_t)blockIdx.x * blockDim.x + threadIdx.x; // float4 index
  size_t fe = idx * 4;
  size_t b = fe / ((size_t)NC * ND);
  size_t rem = fe % ((size_t)NC * ND);
  float4 v = *(const float4*)(h0 + fe);
  *(float4*)(out + (b * NT_) * (size_t)NC * ND + rem) = v;
}

// ---------------------------------------------------------------------------
// invdeg[b*NC+i] = 1 / max(sum_j adj[b,i,j], 1)
__global__ __launch_bounds__(256) void k_deg(const float* __restrict__ adj,
                                             float* __restrict__ invdeg) {
  int wave = threadIdx.x >> 6;
  int lane = threadIdx.x & 63;
  int row = blockIdx.x * 4 + wave; // 0 .. 16383
  const float* p = adj + (size_t)row * NC;
  float s = 0.f;
#pragma unroll
  for (int q = 0; q < 4; ++q) {
    float4 v = *(const float4*)(p + q * 256 + lane * 4);
    s += v.x + v.y + v.z + v.w;
  }
#pragma unroll
  for (int off = 32; off; off >>= 1) s += __shfl_down(s, off);
  if (lane == 0) invdeg[row] = 1.f / fmaxf(s, 1.f);
}

// ---------------------------------------------------------------------------
// adjacency f32 -> fp16 hi/lo split (same layout)
__global__ __launch_bounds__(256) void k_split_adj(const float* __restrict__ adj,
                                                   _Float16* __restrict__ aH,
                                                   _Float16* __restrict__ aL) {
  size_t i4 = (size_t)blockIdx.x * 256 + threadIdx.x; // float4 index
  float4 v = *(const float4*)(adj + i4 * 4);
  half4v h, l;
  float vv[4] = {v.x, v.y, v.z, v.w};
#pragma unroll
  for (int q = 0; q < 4; ++q) {
    _Float16 hh = (_Float16)vv[q];
    h[q] = hh;
    l[q] = (_Float16)(vv[q] - (float)hh);
  }
  *(half4v*)(aH + i4 * 4) = h;
  *(half4v*)(aL + i4 * 4) = l;
}

// ---------------------------------------------------------------------------
// W1[0:512]^T and W2^T -> fp16 hi/lo  (W1T [256][512], W2T [256][256])
__global__ __launch_bounds__(256) void k_split_w(const float* __restrict__ W1,
                                                 const float* __restrict__ W2,
                                                 _Float16* __restrict__ W1TH,
                                                 _Float16* __restrict__ W1TL,
                                                 _Float16* __restrict__ W2TH,
                                                 _Float16* __restrict__ W2TL) {
  int o = blockIdx.x * 256 + threadIdx.x;
  if (o < 256 * 512) {
    int n = o >> 9, k = o & 511;
    float v = W1[(size_t)k * ND + n];
    _Float16 h = (_Float16)v;
    W1TH[o] = h;
    W1TL[o] = (_Float16)(v - (float)h);
  } else {
    int o2 = o - 256 * 512;
    int n = o2 >> 8, k = o2 & 255;
    float v = W2[(size_t)k * ND + n];
    _Float16 h = (_Float16)v;
    W2TH[o2] = h;
    W2TL[o2] = (_Float16)(v - (float)h);
  }
}

// ---------------------------------------------------------------------------
// one-time: h0 (f32 [b][c][d], batch stride bs) -> hH/hL [b][c][d]
//                                                + hTH/hTL [b][d][c]
__global__ __launch_bounds__(256) void k_htsplit(const float* __restrict__ src, long bs,
                                                 _Float16* __restrict__ hH,
                                                 _Float16* __restrict__ hL,
                                                 _Float16* __restrict__ hTH,
                                                 _Float16* __restrict__ hTL) {
  __shared__ float tile[64][65];
  int b = blockIdx.z, c0 = blockIdx.x * 64, d0 = blockIdx.y * 64;
  int t = threadIdx.x;
#pragma unroll
  for (int it = 0; it < 16; ++it) {
    int e = it * 256 + t;
    int cl = e >> 6, dl = e & 63;
    float v = src[(size_t)b * bs + (size_t)(c0 + cl) * ND + d0 + dl];
    _Float16 h = (_Float16)v;
    _Float16 lo = (_Float16)(v - (float)h);
    size_t ni = ((size_t)b * NC + c0 + cl) * ND + d0 + dl;
    hH[ni] = h;
    hL[ni] = lo;
    tile[dl][cl] = v;
  }
  __syncthreads();
#pragma unroll
  for (int it = 0; it < 16; ++it) {
    int e = it * 256 + t;
    int dl = e >> 6, cl = e & 63;
    float v = tile[dl][cl];
    _Float16 h = (_Float16)v;
    _Float16 lo = (_Float16)(v - (float)h);
    size_t ti = ((size_t)b * ND + d0 + dl) * NC + c0 + cl;
    hTH[ti] = h;
    hTL[ti] = lo;
  }
}

// ---------------------------------------------------------------------------
// shared GEMM machinery: A [BM rows][K], B^T [BN rows][K], both fp16 hi/lo,
// K-major, staged to LDS planes [k/8][row][8] via global_load_lds(16B).
__device__ __forceinline__ void stage_A(const _Float16* sH, const _Float16* sL,
                                        long sA, _Float16* AsH, _Float16* AsL,
                                        int wid, int lane) {
#pragma unroll
  for (int c = 0; c < 2; ++c) {
    int nb = c * 256 + wid * 64; // uniform chunk base
    int n = nb + lane;
    int g = n >> 7, r = n & 127;
    GLL(sH + (size_t)r * sA + 8 * g, AsH + (size_t)nb * 8);
    GLL(sL + (size_t)r * sA + 8 * g, AsL + (size_t)nb * 8);
  }
}

__device__ __forceinline__ void stage_B(const _Float16* sH, const _Float16* sL,
                                        long sB, _Float16* BsH, _Float16* BsL,
                                        int wid, int lane) {
  int nb = wid * 64;
  int n = nb + lane;
  int g = n >> 6, r = n & 63;
  GLL(sH + (size_t)r * sB + 8 * g, BsH + (size_t)nb * 8);
  GLL(sL + (size_t)r * sB + 8 * g, BsL + (size_t)nb * 8);
}

__device__ __forceinline__ void mfma_step(const _Float16* AsH, const _Float16* AsL,
                                          const _Float16* BsH, const _Float16* BsL,
                                          int wm, int wn, int lane,
                                          f32x4 acc[4][2]) {
  int g = lane >> 4, r = lane & 15;
  half8 AHf[4], ALf[4], BHf[2], BLf[2];
#pragma unroll
  for (int i = 0; i < 4; ++i) {
    int ch = g * 128 + wm * 64 + i * 16 + r;
    AHf[i] = ((const half8*)AsH)[ch];
    ALf[i] = ((const half8*)AsL)[ch];
  }
#pragma unroll
  for (int j = 0; j < 2; ++j) {
    int ch = g * 64 + wn * 32 + j * 16 + r;
    BHf[j] = ((const half8*)BsH)[ch];
    BLf[j] = ((const half8*)BsL)[ch];
  }
#pragma unroll
  for (int i = 0; i < 4; ++i)
#pragma unroll
    for (int j = 0; j < 2; ++j) {
      acc[i][j] = __builtin_amdgcn_mfma_f32_16x16x32_f16(AHf[i], BHf[j], acc[i][j], 0, 0, 0);
      acc[i][j] = __builtin_amdgcn_mfma_f32_16x16x32_f16(AHf[i], BLf[j], acc[i][j], 0, 0, 0);
      acc[i][j] = __builtin_amdgcn_mfma_f32_16x16x32_f16(ALf[i], BHf[j], acc[i][j], 0, 0, 0);
    }
}

#define GEMM_PRE()                                                             \
  __shared__ __align__(16) _Float16 AsH[2][BM * BK];                           \
  __shared__ __align__(16) _Float16 AsL[2][BM * BK];                           \
  __shared__ __align__(16) _Float16 BsH[2][BN * BK];                           \
  __shared__ __align__(16) _Float16 BsL[2][BN * BK];                           \
  const int tid = threadIdx.x;                                                 \
  const int lane = tid & 63, wid = tid >> 6;                                   \
  const int wm = wid >> 1, wn = wid & 1;                                       \
  f32x4 acc[4][2] = {};

// ---------------------------------------------------------------------------
// GEMM1: agg[b] = diag(invdeg[b]) * (adj[b] @ h[b]); epilogue splits to fp16.
__global__ __launch_bounds__(NTHR) void k_agg(const _Float16* __restrict__ adjH,
                                              const _Float16* __restrict__ adjL,
                                              const _Float16* __restrict__ hTH,
                                              const _Float16* __restrict__ hTL,
                                              const float* __restrict__ invdeg,
                                              _Float16* __restrict__ aggH,
                                              _Float16* __restrict__ aggL) {
  const int b = blockIdx.z;
  const int m0 = blockIdx.x * BM;
  const int n0 = blockIdx.y * BN;
  GEMM_PRE();
  const _Float16* A_H = adjH + (size_t)b * NC * NC + (size_t)m0 * NC;
  const _Float16* A_L = adjL + (size_t)b * NC * NC + (size_t)m0 * NC;
  const _Float16* B_H = hTH + (size_t)b * ND * NC + (size_t)n0 * NC;
  const _Float16* B_L = hTL + (size_t)b * ND * NC + (size_t)n0 * NC;
  const int NTILES = NC / BK; // 32
  stage_A(A_H, A_L, NC, AsH[0], AsL[0], wid, lane);
  stage_B(B_H, B_L, NC, BsH[0], BsL[0], wid, lane);
  __syncthreads();
  for (int t = 0; t < NTILES; ++t) {
    int cur = t & 1;
    if (t + 1 < NTILES) {
      int k0 = (t + 1) * BK;
      stage_A(A_H + k0, A_L + k0, NC, AsH[cur ^ 1], AsL[cur ^ 1], wid, lane);
      stage_B(B_H + k0, B_L + k0, NC, BsH[cur ^ 1], BsL[cur ^ 1], wid, lane);
    }
    mfma_step(AsH[cur], AsL[cur], BsH[cur], BsL[cur], wm, wn, lane, acc);
    __syncthreads();
  }
  int r15 = lane & 15, rg = (lane >> 4) * 4;
#pragma unroll
  for (int i = 0; i < 4; ++i) {
#pragma unroll
    for (int j = 0; j < 2; ++j) {
      int col = n0 + wn * 32 + j * 16 + r15;
#pragma unroll
      for (int q = 0; q < 4; ++q) {
        int m = m0 + wm * 64 + i * 16 + rg + q;
        float v = acc[i][j][q] * invdeg[b * NC + m];
        _Float16 h = (_Float16)v;
        size_t idx = ((size_t)b * NC + m) * ND + col;
        aggH[idx] = h;
        aggL[idx] = (_Float16)(v - (float)h);
      }
    }
  }
}

// ---------------------------------------------------------------------------
// GEMM2: u = tanh([h | agg] @ W1[0:512] + b1eff); b1eff computed in-block.
__global__ __launch_bounds__(NTHR) void k_mlp1(const _Float16* __restrict__ hH,
                                               const _Float16* __restrict__ hL,
                                               const _Float16* __restrict__ aggH,
                                               const _Float16* __restrict__ aggL,
                                               const _Float16* __restrict__ W1TH,
                                               const _Float16* __restrict__ W1TL,
                                               const float* __restrict__ W1,
                                               const float* __restrict__ b1,
                                               const float* __restrict__ tg, int step,
                                               int stage, _Float16* __restrict__ uH,
                                               _Float16* __restrict__ uL) {
  const int m0 = blockIdx.x * BM;
  const int n0 = blockIdx.y * BN;
  const int b = m0 >> 10, c0 = m0 & 1023;
  GEMM_PRE();
  __shared__ float te_s[TDIM];
  __shared__ float b1s[BN];
  const size_t abase = ((size_t)b * NC + c0) * ND;
  const int NTILES = 512 / BK; // 16
  // prologue: stage tile 0 + time embedding
  stage_A(hH + abase, hL + abase, ND, AsH[0], AsL[0], wid, lane);
  stage_B(W1TH + (size_t)n0 * 512, W1TL + (size_t)n0 * 512, 512, BsH[0], BsL[0], wid,
          lane);
  if (tid < 16) {
    float t0 = tg[step], t1 = tg[step + 1];
    float dtt = t1 - t0;
    float frac = (stage == 0) ? 0.f : ((stage == 3) ? 1.f : 0.5f);
    float t = t0 + frac * dtt;
    float f = expf(-logf(10000.f) * (float)tid / 16.f);
    te_s[tid] = sinf(t * f);
    te_s[tid + 16] = cosf(t * f);
  }
  __syncthreads();
  if (tid < BN) {
    int col = n0 + tid;
    float s = b1[col];
#pragma unroll
    for (int q = 0; q < TDIM; ++q)
      s = fmaf(te_s[q], W1[(size_t)(512 + q) * ND + col], s);
    b1s[tid] = s;
  }
  for (int t = 0; t < NTILES; ++t) {
    int cur = t & 1;
    if (t + 1 < NTILES) {
      int k0 = (t + 1) * BK;
      const _Float16 *sH, *sL;
      if (k0 < 256) {
        sH = hH + abase + k0;
        sL = hL + abase + k0;
      } else {
        sH = aggH + abase + (k0 - 256);
        sL = aggL + abase + (k0 - 256);
      }
      stage_A(sH, sL, ND, AsH[cur ^ 1], AsL[cur ^ 1], wid, lane);
      stage_B(W1TH + (size_t)n0 * 512 + k0, W1TL + (size_t)n0 * 512 + k0, 512,
              BsH[cur ^ 1], BsL[cur ^ 1], wid, lane);
    }
    mfma_step(AsH[cur], AsL[cur], BsH[cur], BsL[cur], wm, wn, lane, acc);
    __syncthreads();
  }
  int r15 = lane & 15, rg = (lane >> 4) * 4;
#pragma unroll
  for (int i = 0; i < 4; ++i) {
#pragma unroll
    for (int j = 0; j < 2; ++j) {
      int cl = wn * 32 + j * 16 + r15;
      int col = n0 + cl;
#pragma unroll
      for (int q = 0; q < 4; ++q) {
        int m = m0 + wm * 64 + i * 16 + rg + q;
        float v = tanhf(acc[i][j][q] + b1s[cl]);
        _Float16 h = (_Float16)v;
        size_t idx = (size_t)m * ND + col;
        uH[idx] = h;
        uL[idx] = (_Float16)(v - (float)h);
      }
    }
  }
}

// ---------------------------------------------------------------------------
// GEMM3 + RK4 stage epilogue: f = u @ W2 + b2; writes next-h splits directly.
// stage 0: accws = f;        hnext = hb + 0.5*dt*f
// stage 1: accws += 2f;      hnext = hb + 0.5*dt*f
// stage 2: accws += 2f;      hnext = hb + dt*f
// stage 3: hnext = hb + dt/6*(accws + f); also out[:,step+1] = hnext (f32)
__global__ __launch_bounds__(NTHR) void k_mlp2(const _Float16* __restrict__ uH,
                                               const _Float16* __restrict__ uL,
                                               const _Float16* __restrict__ W2TH,
                                               const _Float16* __restrict__ W2TL,
                                               const float* __restrict__ b2,
                                               const float* __restrict__ tg, int step,
                                               int stage, float* __restrict__ out,
                                               float* __restrict__ accws,
                                               _Float16* __restrict__ hH,
                                               _Float16* __restrict__ hL,
                                               _Float16* __restrict__ hTH,
                                               _Float16* __restrict__ hTL) {
  const int m0 = blockIdx.x * BM;
  const int n0 = blockIdx.y * BN;
  GEMM_PRE();
  const int NTILES = ND / BK; // 8
  stage_A(uH + (size_t)m0 * ND, uL + (size_t)m0 * ND, ND, AsH[0], AsL[0], wid, lane);
  stage_B(W2TH + (size_t)n0 * ND, W2TL + (size_t)n0 * ND, ND, BsH[0], BsL[0], wid, lane);
  __syncthreads();
  for (int t = 0; t < NTILES; ++t) {
    int cur = t & 1;
    if (t + 1 < NTILES) {
      int k0 = (t + 1) * BK;
      stage_A(uH + (size_t)m0 * ND + k0, uL + (size_t)m0 * ND + k0, ND, AsH[cur ^ 1],
              AsL[cur ^ 1], wid, lane);
      stage_B(W2TH + (size_t)n0 * ND + k0, W2TL + (size_t)n0 * ND + k0, ND, BsH[cur ^ 1],
              BsL[cur ^ 1], wid, lane);
    }
    mfma_step(AsH[cur], AsL[cur], BsH[cur], BsL[cur], wm, wn, lane, acc);
    __syncthreads();
  }
  const float t0 = tg[step], t1 = tg[step + 1];
  const float dt = t1 - t0;
  const float cs = (stage == 2) ? dt : 0.5f * dt;
  int r15 = lane & 15, rg = (lane >> 4) * 4;
#pragma unroll
  for (int i = 0; i < 4; ++i) {
#pragma unroll
    for (int j = 0; j < 2; ++j) {
      int col = n0 + wn * 32 + j * 16 + r15;
      float bb2 = b2[col];
      int mbase = m0 + wm * 64 + i * 16 + rg; // multiple of 4, same b for q=0..3
      int b = mbase >> 10, ii0 = mbase & 1023;
      size_t hrow = (((size_t)b * NT_ + step) * NC + ii0) * (size_t)ND + col;
      size_t wrow = (size_t)mbase * ND + col;
      float val[4];
#pragma unroll
      for (int q = 0; q < 4; ++q) {
        float f = acc[i][j][q] + bb2;
        float hb = out[hrow + (size_t)q * ND];
        size_t widx = wrow + (size_t)q * ND;
        if (stage == 0) {
          accws[widx] = f;
          val[q] = hb + cs * f;
        } else if (stage == 3) {
          float hn = hb + (dt / 6.f) * (accws[widx] + f);
          out[hrow + (size_t)NC * ND + (size_t)q * ND] = hn; // traj[:,step+1]
          val[q] = hn;
        } else {
          accws[widx] += 2.f * f;
          val[q] = hb + cs * f;
        }
      }
      half4v th, tl;
#pragma unroll
      for (int q = 0; q < 4; ++q) {
        _Float16 hh = (_Float16)val[q];
        th[q] = hh;
        tl[q] = (_Float16)(val[q] - (float)hh);
      }
      size_t nrow = ((size_t)b * NC + ii0) * ND + col;
#pragma unroll
      for (int q = 0; q < 4; ++q) {
        hH[nrow + (size_t)q * ND] = th[q];
        hL[nrow + (size_t)q * ND] = tl[q];
      }
      size_t trow = ((size_t)b * ND + col) * NC + ii0;
      *(half4v*)(hTH + trow) = th;
      *(half4v*)(hTL + trow) = tl;
    }
  }
}

// ---------------------------------------------------------------------------
extern "C" void kernel_launch(void* const* d_in, const int* in_sizes, int n_in,
                              void* d_out, int out_size, void* d_ws, size_t ws_size,
                              hipStream_t stream) {
  const float* h0 = (const float*)d_in[0];
  const float* tg = (const float*)d_in[1];
  const float* adj = (const float*)d_in[2];
  const float* W1 = (const float*)d_in[3];
  const float* b1 = (const float*)d_in[4];
  const float* W2 = (const float*)d_in[5];
  const float* b2 = (const float*)d_in[6];
  float* out = (float*)d_out;

  const size_t CD = (size_t)NC * ND; // 262144
  char* w = (char*)d_ws;
  float* invdeg = (float*)w;     w += (size_t)16384 * 4;
  float* accws = (float*)w;      w += (size_t)NB * CD * 4;
  _Float16* adjH = (_Float16*)w; w += (size_t)NB * NC * NC * 2;
  _Float16* adjL = (_Float16*)w; w += (size_t)NB * NC * NC * 2;
  _Float16* hH = (_Float16*)w;   w += (size_t)NB * CD * 2;
  _Float16* hL = (_Float16*)w;   w += (size_t)NB * CD * 2;
  _Float16* hTH = (_Float16*)w;  w += (size_t)NB * CD * 2;
  _Float16* hTL = (_Float16*)w;  w += (size_t)NB * CD * 2;
  _Float16* aggH = (_Float16*)w; w += (size_t)NB * CD * 2;
  _Float16* aggL = (_Float16*)w; w += (size_t)NB * CD * 2;
  _Float16* uH = (_Float16*)w;   w += (size_t)NB * CD * 2;
  _Float16* uL = (_Float16*)w;   w += (size_t)NB * CD * 2;
  _Float16* W1TH = (_Float16*)w; w += (size_t)256 * 512 * 2;
  _Float16* W1TL = (_Float16*)w; w += (size_t)256 * 512 * 2;
  _Float16* W2TH = (_Float16*)w; w += (size_t)256 * 256 * 2;
  _Float16* W2TL = (_Float16*)w; w += (size_t)256 * 256 * 2;

  k_copy_h0<<<dim3(4096), dim3(256), 0, stream>>>(h0, out);
  k_deg<<<dim3(4096), dim3(256), 0, stream>>>(adj, invdeg);
  k_split_adj<<<dim3(16384), dim3(256), 0, stream>>>(adj, adjH, adjL);
  k_split_w<<<dim3(768), dim3(256), 0, stream>>>(W1, W2, W1TH, W1TL, W2TH, W2TL);
  k_htsplit<<<dim3(16, 4, 16), dim3(256), 0, stream>>>(h0, (long)CD, hH, hL, hTH, hTL);

  for (int s = 0; s < NT_ - 1; ++s) {
    for (int st = 0; st < 4; ++st) {
      k_agg<<<dim3(8, 4, 16), dim3(NTHR), 0, stream>>>(adjH, adjL, hTH, hTL, invdeg,
                                                       aggH, aggL);
      k_mlp1<<<dim3(128, 4), dim3(NTHR), 0, stream>>>(hH, hL, aggH, aggL, W1TH, W1TL,
                                                      W1, b1, tg, s, st, uH, uL);
      k_mlp2<<<dim3(128, 4), dim3(NTHR), 0, stream>>>(uH, uL, W2TH, W2TL, b2, tg, s, st,
                                                      out, accws, hH, hL, hTH, hTL);
    }
  }
}

// Round 4
// 3135.297 us; speedup vs baseline: 1.4295x; 1.4295x over previous
//
#include <hip/hip_runtime.h>
#include <math.h>

// Problem dims
#define NB   16
#define NC   1024
#define ND   256
#define NT_  9
#define TDIM 32

// GEMM tile config: 128x64 tile, BK=32, 256 threads (4 waves, 2x2),
// wave tile 64x32 = 4x2 fragments of 16x16.
#define BM 128
#define BN 64
#define BK 32
#define NTHR 256

typedef _Float16 half8 __attribute__((ext_vector_type(8)));
typedef _Float16 half4v __attribute__((ext_vector_type(4)));
typedef float f32x4 __attribute__((ext_vector_type(4)));

#define GLL(gp, lp)                                                            \
  __builtin_amdgcn_global_load_lds(                                            \
      (const __attribute__((address_space(1))) void*)(gp),                     \
      (__attribute__((address_space(3))) void*)(lp), 16, 0, 0)

// ---------------------------------------------------------------------------
// copy h0 -> traj[:,0]
__global__ __launch_bounds__(256) void k_copy_h0(const float* __restrict__ h0,
                                                 float* __restrict__ out) {
  size_t idx = (size_t)blockIdx.x * blockDim.x + threadIdx.x; // float4 index
  size_t fe = idx * 4;
  size_t b = fe / ((size_t)NC * ND);
  size_t rem = fe % ((size_t)NC * ND);
  float4 v = *(const float4*)(h0 + fe);
  *(float4*)(out + (b * NT_) * (size_t)NC * ND + rem) = v;
}

// ---------------------------------------------------------------------------
// invdeg[b*NC+i] = 1 / max(sum_j adj[b,i,j], 1)
__global__ __launch_bounds__(256) void k_deg(const float* __restrict__ adj,
                                             float* __restrict__ invdeg) {
  int wave = threadIdx.x >> 6;
  int lane = threadIdx.x & 63;
  int row = blockIdx.x * 4 + wave; // 0 .. 16383
  const float* p = adj + (size_t)row * NC;
  float s = 0.f;
#pragma unroll
  for (int q = 0; q < 4; ++q) {
    float4 v = *(const float4*)(p + q * 256 + lane * 4);
    s += v.x + v.y + v.z + v.w;
  }
#pragma unroll
  for (int off = 32; off; off >>= 1) s += __shfl_down(s, off);
  if (lane == 0) invdeg[row] = 1.f / fmaxf(s, 1.f);
}

// ---------------------------------------------------------------------------
// adjacency f32 -> fp16 (hi only; rounding error averages out under the
// degree-normalized sum — see round-4 analysis)
__global__ __launch_bounds__(256) void k_split_adj(const float* __restrict__ adj,
                                                   _Float16* __restrict__ aH) {
  size_t i4 = (size_t)blockIdx.x * 256 + threadIdx.x; // float4 index
  float4 v = *(const float4*)(adj + i4 * 4);
  half4v h;
  h[0] = (_Float16)v.x; h[1] = (_Float16)v.y;
  h[2] = (_Float16)v.z; h[3] = (_Float16)v.w;
  *(half4v*)(aH + i4 * 4) = h;
}

// ---------------------------------------------------------------------------
// W1[0:512]^T and W2^T -> fp16 hi/lo  (W1T [256][512], W2T [256][256])
__global__ __launch_bounds__(256) void k_split_w(const float* __restrict__ W1,
                                                 const float* __restrict__ W2,
                                                 _Float16* __restrict__ W1TH,
                                                 _Float16* __restrict__ W1TL,
                                                 _Float16* __restrict__ W2TH,
                                                 _Float16* __restrict__ W2TL) {
  int o = blockIdx.x * 256 + threadIdx.x;
  if (o < 256 * 512) {
    int n = o >> 9, k = o & 511;
    float v = W1[(size_t)k * ND + n];
    _Float16 h = (_Float16)v;
    W1TH[o] = h;
    W1TL[o] = (_Float16)(v - (float)h);
  } else {
    int o2 = o - 256 * 512;
    int n = o2 >> 8, k = o2 & 255;
    float v = W2[(size_t)k * ND + n];
    _Float16 h = (_Float16)v;
    W2TH[o2] = h;
    W2TL[o2] = (_Float16)(v - (float)h);
  }
}

// ---------------------------------------------------------------------------
// one-time: h0 (f32 [b][c][d]) -> hH/hL [b][c][d] + hTH [b][d][c]
__global__ __launch_bounds__(256) void k_htsplit(const float* __restrict__ src,
                                                 _Float16* __restrict__ hH,
                                                 _Float16* __restrict__ hL,
                                                 _Float16* __restrict__ hTH) {
  __shared__ _Float16 tile[64][65];
  int b = blockIdx.z, c0 = blockIdx.x * 64, d0 = blockIdx.y * 64;
  int t = threadIdx.x;
#pragma unroll
  for (int it = 0; it < 16; ++it) {
    int e = it * 256 + t;
    int cl = e >> 6, dl = e & 63;
    float v = src[((size_t)b * NC + c0 + cl) * ND + d0 + dl];
    _Float16 h = (_Float16)v;
    _Float16 lo = (_Float16)(v - (float)h);
    size_t ni = ((size_t)b * NC + c0 + cl) * ND + d0 + dl;
    hH[ni] = h;
    hL[ni] = lo;
    tile[dl][cl] = h;
  }
  __syncthreads();
#pragma unroll
  for (int it = 0; it < 16; ++it) {
    int e = it * 256 + t;
    int dl = e >> 6, cl = e & 63;
    size_t ti = ((size_t)b * ND + d0 + dl) * NC + c0 + cl;
    hTH[ti] = tile[dl][cl];
  }
}

// ---------------------------------------------------------------------------
// stage ROWS x 32 halves (K-major rows, stride in halves) into LDS plane-major
// chunks [g][row][8], chunk index = g*ROWS + row.
template <int ROWS>
__device__ __forceinline__ void stage_t(const _Float16* src, long stride,
                                        _Float16* dst, int wid, int lane) {
#pragma unroll
  for (int c = 0; c < ROWS / 64; ++c) {
    int nb = c * 256 + wid * 64;
    int n = nb + lane;
    int g = n / ROWS, r = n % ROWS;
    GLL(src + (size_t)r * stride + 8 * g, dst + (size_t)nb * 8);
  }
}

// 3-product hi/lo MFMA step (A 128 rows, B 64 rows, 4x2 frags)
__device__ __forceinline__ void mfma_3p(const _Float16* AsH, const _Float16* AsL,
                                        const _Float16* BsH, const _Float16* BsL,
                                        int wm, int wn, int lane, f32x4 acc[4][2]) {
  int g = lane >> 4, r = lane & 15;
  half8 AHf[4], ALf[4], BHf[2], BLf[2];
#pragma unroll
  for (int i = 0; i < 4; ++i) {
    int ch = g * 128 + wm * 64 + i * 16 + r;
    AHf[i] = ((const half8*)AsH)[ch];
    ALf[i] = ((const half8*)AsL)[ch];
  }
#pragma unroll
  for (int j = 0; j < 2; ++j) {
    int ch = g * 64 + wn * 32 + j * 16 + r;
    BHf[j] = ((const half8*)BsH)[ch];
    BLf[j] = ((const half8*)BsL)[ch];
  }
#pragma unroll
  for (int i = 0; i < 4; ++i)
#pragma unroll
    for (int j = 0; j < 2; ++j) {
      acc[i][j] = __builtin_amdgcn_mfma_f32_16x16x32_f16(AHf[i], BHf[j], acc[i][j], 0, 0, 0);
      acc[i][j] = __builtin_amdgcn_mfma_f32_16x16x32_f16(AHf[i], BLf[j], acc[i][j], 0, 0, 0);
      acc[i][j] = __builtin_amdgcn_mfma_f32_16x16x32_f16(ALf[i], BHf[j], acc[i][j], 0, 0, 0);
    }
}

// single-product MFMA step (A 128 rows, B 64 rows, 4x2 frags)
__device__ __forceinline__ void mfma_1p(const _Float16* As, const _Float16* Bs,
                                        int wm, int wn, int lane, f32x4 acc[4][2]) {
  int g = lane >> 4, r = lane & 15;
  half8 Af[4], Bf[2];
#pragma unroll
  for (int i = 0; i < 4; ++i)
    Af[i] = ((const half8*)As)[g * 128 + wm * 64 + i * 16 + r];
#pragma unroll
  for (int j = 0; j < 2; ++j)
    Bf[j] = ((const half8*)Bs)[g * 64 + wn * 32 + j * 16 + r];
#pragma unroll
  for (int i = 0; i < 4; ++i)
#pragma unroll
    for (int j = 0; j < 2; ++j)
      acc[i][j] = __builtin_amdgcn_mfma_f32_16x16x32_f16(Af[i], Bf[j], acc[i][j], 0, 0, 0);
}

// ---------------------------------------------------------------------------
// GEMM1 (single-product fp16): agg[b] = diag(invdeg[b]) * (adjH[b] @ hH[b])
// double-buffered LDS (24KB total -> 6 blocks/CU)
__global__ __launch_bounds__(NTHR) void k_agg(const _Float16* __restrict__ adjH,
                                              const _Float16* __restrict__ hTH,
                                              const float* __restrict__ invdeg,
                                              _Float16* __restrict__ aggH,
                                              _Float16* __restrict__ aggL) {
  const int b = blockIdx.z;
  const int m0 = blockIdx.x * BM;
  const int n0 = blockIdx.y * BN;
  __shared__ __align__(16) _Float16 As[2][BM * BK];
  __shared__ __align__(16) _Float16 Bs[2][BN * BK];
  const int tid = threadIdx.x;
  const int lane = tid & 63, wid = tid >> 6;
  const int wm = wid >> 1, wn = wid & 1;
  f32x4 acc[4][2] = {};
  const _Float16* A = adjH + (size_t)b * NC * NC + (size_t)m0 * NC;
  const _Float16* Bp = hTH + (size_t)b * ND * NC + (size_t)n0 * NC;
  const int NTILES = NC / BK; // 32
  stage_t<BM>(A, NC, As[0], wid, lane);
  stage_t<BN>(Bp, NC, Bs[0], wid, lane);
  __syncthreads();
  for (int t = 0; t < NTILES; ++t) {
    int cur = t & 1;
    if (t + 1 < NTILES) {
      int k0 = (t + 1) * BK;
      stage_t<BM>(A + k0, NC, As[cur ^ 1], wid, lane);
      stage_t<BN>(Bp + k0, NC, Bs[cur ^ 1], wid, lane);
    }
    mfma_1p(As[cur], Bs[cur], wm, wn, lane, acc);
    __syncthreads();
  }
  int r15 = lane & 15, rg = (lane >> 4) * 4;
#pragma unroll
  for (int i = 0; i < 4; ++i) {
#pragma unroll
    for (int j = 0; j < 2; ++j) {
      int col = n0 + wn * 32 + j * 16 + r15;
#pragma unroll
      for (int q = 0; q < 4; ++q) {
        int m = m0 + wm * 64 + i * 16 + rg + q;
        float v = acc[i][j][q] * invdeg[b * NC + m];
        _Float16 h = (_Float16)v;
        size_t idx = ((size_t)b * NC + m) * ND + col;
        aggH[idx] = h;
        aggL[idx] = (_Float16)(v - (float)h);
      }
    }
  }
}

// ---------------------------------------------------------------------------
// GEMM2 (3-product): u = tanh([h | agg] @ W1[0:512] + b1eff); b1eff in-block.
// serial single-buffer schedule (24KB LDS)
__global__ __launch_bounds__(NTHR) void k_mlp1(const _Float16* __restrict__ hH,
                                               const _Float16* __restrict__ hL,
                                               const _Float16* __restrict__ aggH,
                                               const _Float16* __restrict__ aggL,
                                               const _Float16* __restrict__ W1TH,
                                               const _Float16* __restrict__ W1TL,
                                               const float* __restrict__ W1,
                                               const float* __restrict__ b1,
                                               const float* __restrict__ tg, int step,
                                               int stage, _Float16* __restrict__ uH,
                                               _Float16* __restrict__ uL) {
  const int m0 = blockIdx.x * BM;
  const int n0 = blockIdx.y * BN;
  const int b = m0 >> 10, c0 = m0 & 1023;
  __shared__ __align__(16) _Float16 AsH[BM * BK];
  __shared__ __align__(16) _Float16 AsL[BM * BK];
  __shared__ __align__(16) _Float16 BsH[BN * BK];
  __shared__ __align__(16) _Float16 BsL[BN * BK];
  __shared__ float te_s[TDIM];
  __shared__ float b1s[BN];
  const int tid = threadIdx.x;
  const int lane = tid & 63, wid = tid >> 6;
  const int wm = wid >> 1, wn = wid & 1;
  f32x4 acc[4][2] = {};
  const size_t abase = ((size_t)b * NC + c0) * ND;
  if (tid < 16) {
    float t0 = tg[step], t1 = tg[step + 1];
    float dtt = t1 - t0;
    float frac = (stage == 0) ? 0.f : ((stage == 3) ? 1.f : 0.5f);
    float t = t0 + frac * dtt;
    float f = expf(-logf(10000.f) * (float)tid / 16.f);
    te_s[tid] = sinf(t * f);
    te_s[tid + 16] = cosf(t * f);
  }
  __syncthreads();
  if (tid < BN) {
    int col = n0 + tid;
    float s = b1[col];
#pragma unroll
    for (int q = 0; q < TDIM; ++q)
      s = fmaf(te_s[q], W1[(size_t)(512 + q) * ND + col], s);
    b1s[tid] = s;
  }
  for (int k0 = 0; k0 < 512; k0 += BK) {
    const _Float16 *sH, *sL;
    if (k0 < 256) {
      sH = hH + abase + k0;
      sL = hL + abase + k0;
    } else {
      sH = aggH + abase + (k0 - 256);
      sL = aggL + abase + (k0 - 256);
    }
    stage_t<BM>(sH, ND, AsH, wid, lane);
    stage_t<BM>(sL, ND, AsL, wid, lane);
    stage_t<BN>(W1TH + (size_t)n0 * 512 + k0, 512, BsH, wid, lane);
    stage_t<BN>(W1TL + (size_t)n0 * 512 + k0, 512, BsL, wid, lane);
    asm volatile("s_waitcnt vmcnt(0)" ::: "memory");
    __syncthreads();
    mfma_3p(AsH, AsL, BsH, BsL, wm, wn, lane, acc);
    __syncthreads();
  }
  int r15 = lane & 15, rg = (lane >> 4) * 4;
#pragma unroll
  for (int i = 0; i < 4; ++i) {
#pragma unroll
    for (int j = 0; j < 2; ++j) {
      int cl = wn * 32 + j * 16 + r15;
      int col = n0 + cl;
#pragma unroll
      for (int q = 0; q < 4; ++q) {
        int m = m0 + wm * 64 + i * 16 + rg + q;
        float v = tanhf(acc[i][j][q] + b1s[cl]);
        _Float16 h = (_Float16)v;
        size_t idx = (size_t)m * ND + col;
        uH[idx] = h;
        uL[idx] = (_Float16)(v - (float)h);
      }
    }
  }
}

// ---------------------------------------------------------------------------
// GEMM3 (3-product) + RK4 stage epilogue: f = u @ W2 + b2
// stage 0: accws = f;   hnext = hb + 0.5*dt*f
// stage 1: accws += 2f; hnext = hb + 0.5*dt*f
// stage 2: accws += 2f; hnext = hb + dt*f
// stage 3: hnext = hb + dt/6*(accws + f); out[:,step+1] = hnext (f32)
__global__ __launch_bounds__(NTHR) void k_mlp2(const _Float16* __restrict__ uH,
                                               const _Float16* __restrict__ uL,
                                               const _Float16* __restrict__ W2TH,
                                               const _Float16* __restrict__ W2TL,
                                               const float* __restrict__ b2,
                                               const float* __restrict__ tg, int step,
                                               int stage, float* __restrict__ out,
                                               float* __restrict__ accws,
                                               _Float16* __restrict__ hH,
                                               _Float16* __restrict__ hL,
                                               _Float16* __restrict__ hTH) {
  const int m0 = blockIdx.x * BM;
  const int n0 = blockIdx.y * BN;
  __shared__ __align__(16) _Float16 AsH[BM * BK];
  __shared__ __align__(16) _Float16 AsL[BM * BK];
  __shared__ __align__(16) _Float16 BsH[BN * BK];
  __shared__ __align__(16) _Float16 BsL[BN * BK];
  const int tid = threadIdx.x;
  const int lane = tid & 63, wid = tid >> 6;
  const int wm = wid >> 1, wn = wid & 1;
  f32x4 acc[4][2] = {};
  for (int k0 = 0; k0 < ND; k0 += BK) {
    stage_t<BM>(uH + (size_t)m0 * ND + k0, ND, AsH, wid, lane);
    stage_t<BM>(uL + (size_t)m0 * ND + k0, ND, AsL, wid, lane);
    stage_t<BN>(W2TH + (size_t)n0 * ND + k0, ND, BsH, wid, lane);
    stage_t<BN>(W2TL + (size_t)n0 * ND + k0, ND, BsL, wid, lane);
    asm volatile("s_waitcnt vmcnt(0)" ::: "memory");
    __syncthreads();
    mfma_3p(AsH, AsL, BsH, BsL, wm, wn, lane, acc);
    __syncthreads();
  }
  const float t0 = tg[step], t1 = tg[step + 1];
  const float dt = t1 - t0;
  const float cs = (stage == 2) ? dt : 0.5f * dt;
  int r15 = lane & 15, rg = (lane >> 4) * 4;
#pragma unroll
  for (int i = 0; i < 4; ++i) {
#pragma unroll
    for (int j = 0; j < 2; ++j) {
      int col = n0 + wn * 32 + j * 16 + r15;
      float bb2 = b2[col];
      int mbase = m0 + wm * 64 + i * 16 + rg; // multiple of 4, same b for q=0..3
      int b = mbase >> 10, ii0 = mbase & 1023;
      size_t hrow = (((size_t)b * NT_ + step) * NC + ii0) * (size_t)ND + col;
      size_t wrow = (size_t)mbase * ND + col;
      float val[4];
#pragma unroll
      for (int q = 0; q < 4; ++q) {
        float f = acc[i][j][q] + bb2;
        float hb = out[hrow + (size_t)q * ND];
        size_t widx = wrow + (size_t)q * ND;
        if (stage == 0) {
          accws[widx] = f;
          val[q] = hb + cs * f;
        } else if (stage == 3) {
          float hn = hb + (dt / 6.f) * (accws[widx] + f);
          out[hrow + (size_t)NC * ND + (size_t)q * ND] = hn; // traj[:,step+1]
          val[q] = hn;
        } else {
          accws[widx] += 2.f * f;
          val[q] = hb + cs * f;
        }
      }
      half4v th;
#pragma unroll
      for (int q = 0; q < 4; ++q) {
        _Float16 hh = (_Float16)val[q];
        th[q] = hh;
        size_t ni = ((size_t)b * NC + ii0 + q) * ND + col;
        hH[ni] = hh;
        hL[ni] = (_Float16)(val[q] - (float)hh);
      }
      size_t trow = ((size_t)b * ND + col) * NC + ii0;
      *(half4v*)(hTH + trow) = th;
    }
  }
}

// ---------------------------------------------------------------------------
extern "C" void kernel_launch(void* const* d_in, const int* in_sizes, int n_in,
                              void* d_out, int out_size, void* d_ws, size_t ws_size,
                              hipStream_t stream) {
  const float* h0 = (const float*)d_in[0];
  const float* tg = (const float*)d_in[1];
  const float* adj = (const float*)d_in[2];
  const float* W1 = (const float*)d_in[3];
  const float* b1 = (const float*)d_in[4];
  const float* W2 = (const float*)d_in[5];
  const float* b2 = (const float*)d_in[6];
  float* out = (float*)d_out;

  const size_t CD = (size_t)NC * ND; // 262144
  char* w = (char*)d_ws;
  float* invdeg = (float*)w;     w += (size_t)16384 * 4;
  float* accws = (float*)w;      w += (size_t)NB * CD * 4;
  _Float16* adjH = (_Float16*)w; w += (size_t)NB * NC * NC * 2;
  _Float16* hH = (_Float16*)w;   w += (size_t)NB * CD * 2;
  _Float16* hL = (_Float16*)w;   w += (size_t)NB * CD * 2;
  _Float16* hTH = (_Float16*)w;  w += (size_t)NB * CD * 2;
  _Float16* aggH = (_Float16*)w; w += (size_t)NB * CD * 2;
  _Float16* aggL = (_Float16*)w; w += (size_t)NB * CD * 2;
  _Float16* uH = (_Float16*)w;   w += (size_t)NB * CD * 2;
  _Float16* uL = (_Float16*)w;   w += (size_t)NB * CD * 2;
  _Float16* W1TH = (_Float16*)w; w += (size_t)256 * 512 * 2;
  _Float16* W1TL = (_Float16*)w; w += (size_t)256 * 512 * 2;
  _Float16* W2TH = (_Float16*)w; w += (size_t)256 * 256 * 2;
  _Float16* W2TL = (_Float16*)w; w += (size_t)256 * 256 * 2;

  k_copy_h0<<<dim3(4096), dim3(256), 0, stream>>>(h0, out);
  k_deg<<<dim3(4096), dim3(256), 0, stream>>>(adj, invdeg);
  k_split_adj<<<dim3(16384), dim3(256), 0, stream>>>(adj, adjH);
  k_split_w<<<dim3(768), dim3(256), 0, stream>>>(W1, W2, W1TH, W1TL, W2TH, W2TL);
  k_htsplit<<<dim3(16, 4, 16), dim3(256), 0, stream>>>(h0, hH, hL, hTH);

  for (int s = 0; s < NT_ - 1; ++s) {
    for (int st = 0; st < 4; ++st) {
      k_agg<<<dim3(8, 4, 16), dim3(NTHR), 0, stream>>>(adjH, hTH, invdeg, aggH, aggL);
      k_mlp1<<<dim3(128, 4), dim3(NTHR), 0, stream>>>(hH, hL, aggH, aggL, W1TH, W1TL,
                                                      W1, b1, tg, s, st, uH, uL);
      k_mlp2<<<dim3(128, 4), dim3(NTHR), 0, stream>>>(uH, uL, W2TH, W2TL, b2, tg, s, st,
                                                      out, accws, hH, hL, hTH);
    }
  }
}